// Round 9
// baseline (137.820 us; speedup 1.0000x reference)
//
#include <hip/hip_runtime.h>

#define NA 15
#define GH 34
#define GW 34
#define SP (GH*GW)          // 1156
#define NB (SP*NA)          // 17340
#define MAXC 5000
#define TOPN 300
#define NW 80               // padded words per mask row (79 used + 1 pad)
#define NRALLOC 5056        // mask rows allocated (79 blocks * 64)
#define THRESH_OBJ 0.2f
#define NMS_T 0.7f
// score-bucket constants: positive-float bits are order-preserving
#define SH 12
#define BLO 0x3E4CCu        // bits(0.2f) >> 12
#define NBUCK 5120          // covers bits(1.0)>>12 - BLO = 4916, 5 per scan-thread

typedef unsigned long long u64;
typedef unsigned int u32;
typedef __attribute__((ext_vector_type(4))) unsigned int u32x4;

__constant__ float c_aw[NA] = {45.3f,32.0f,22.6f,90.5f,64.0f,45.3f,181.0f,128.0f,90.5f,271.5f,192.0f,135.8f,362.0f,256.0f,181.0f};
__constant__ float c_ah[NA] = {22.6f,32.0f,45.3f,45.3f,64.0f,90.5f,90.5f,128.0f,181.0f,135.8f,192.0f,271.5f,181.0f,256.0f,362.0f};

// ---------------- decode: anchors + deltas -> clipped proposals + score bits ----------------
__global__ __launch_bounds__(256) void k_decode(
    const float* __restrict__ cls, const float* __restrict__ pred,
    const int* __restrict__ iminfo, const float* __restrict__ mean,
    const float* __restrict__ stdv, float* __restrict__ boxes,
    u32* __restrict__ sbits) {
#pragma clang fp contract(off)
  int r = blockIdx.x * 256 + threadIdx.x;
  if (r >= NB) return;
  int n = r % NA;
  int p = r / NA;       // p = h*GW + w
  int w = p % GW;
  int h = p / GW;

  float score = cls[(NA + n) * SP + p];             // channel NA+n, spatial p

  float d0 = pred[(n*4+0)*SP + p] * stdv[0] + mean[0];
  float d1 = pred[(n*4+1)*SP + p] * stdv[1] + mean[1];
  float d2 = pred[(n*4+2)*SP + p] * stdv[2] + mean[2];
  float d3 = pred[(n*4+3)*SP + p] * stdv[3] + mean[3];

  float aw = c_aw[n], ah = c_ah[n];
  float sx = (float)(w * 16);
  float sy = (float)(h * 16);
  float xmin = -0.5f * (aw - 1.0f) + sx;
  float ymin = -0.5f * (ah - 1.0f) + sy;
  float xmax =  0.5f * (aw - 1.0f) + sx;
  float ymax =  0.5f * (ah - 1.0f) + sy;

  float widths  = xmax - xmin + 1.0f;
  float heights = ymax - ymin + 1.0f;
  float ctrx = xmin + 0.5f * (widths - 1.0f);
  float ctry = ymin + 0.5f * (heights - 1.0f);

  float pcx = d0 * widths + ctrx;
  float pcy = d1 * heights + ctry;
  float pw = expf(d2) * widths;
  float ph = expf(d3) * heights;

  float x1 = pcx - 0.5f * (pw - 1.0f);
  float y1 = pcy - 0.5f * (ph - 1.0f);
  float x2 = pcx + 0.5f * (pw - 1.0f);
  float y2 = pcy + 0.5f * (ph - 1.0f);

  float ow = (float)iminfo[1] - 1.0f;
  float oh = (float)iminfo[0] - 1.0f;
  x1 = fminf(fmaxf(x1, 0.0f), ow);
  x2 = fminf(fmaxf(x2, 0.0f), ow);
  y1 = fminf(fmaxf(y1, 0.0f), oh);
  y2 = fminf(fmaxf(y2, 0.0f), oh);

  float ws = x2 - x1 + 1.0f;
  float hs = y2 - y1 + 1.0f;
  bool keep = (score > THRESH_OBJ) && (ws >= 6.0f) && (hs >= 6.0f);

  boxes[r*4+0] = x1;
  boxes[r*4+1] = y1;
  boxes[r*4+2] = x2;
  boxes[r*4+3] = y2;
  sbits[r] = keep ? __float_as_uint(score) : 0u;
}

// ------- fused: LDS histogram -> suffix scan -> base[], cnt -> bucket placement -------
__global__ __launch_bounds__(1024) void k_bucket(const u32* __restrict__ sbits,
    int* __restrict__ base, int* __restrict__ cnt, u64* __restrict__ blist) {
  __shared__ int sh[NBUCK];
  __shared__ int fl[NBUCK];
  __shared__ int ch[1024];
  int tid = threadIdx.x;
  for (int j = tid; j < NBUCK; j += 1024) { sh[j] = 0; fl[j] = 0; }
  __syncthreads();
  for (int j = tid; j < NB; j += 1024) {
    u32 bits = sbits[j];
    if (bits) { int b = min((int)((bits >> SH) - BLO), NBUCK - 1); atomicAdd(&sh[b], 1); }
  }
  __syncthreads();
  int c0 = sh[tid*5+0], c1 = sh[tid*5+1], c2 = sh[tid*5+2], c3 = sh[tid*5+3], c4 = sh[tid*5+4];
  ch[tid] = c0 + c1 + c2 + c3 + c4;
  __syncthreads();
  // Hillis-Steele inclusive suffix scan over chunk sums
  for (int off = 1; off < 1024; off <<= 1) {
    int v = ch[tid];
    int u = (tid + off < 1024) ? ch[tid + off] : 0;
    __syncthreads();
    ch[tid] = v + u;
    __syncthreads();
  }
  int S = (tid + 1 < 1024) ? ch[tid + 1] : 0;   // exclusive suffix of chunks after tid
  int b4v = S;
  int b3v = b4v + c4;
  int b2v = b3v + c3;
  int b1v = b2v + c2;
  int b0v = b1v + c1;
  base[tid*5+0] = b0v; base[tid*5+1] = b1v; base[tid*5+2] = b2v;
  base[tid*5+3] = b3v; base[tid*5+4] = b4v;
  sh[tid*5+0] = b0v; sh[tid*5+1] = b1v; sh[tid*5+2] = b2v;   // reuse sh as base
  sh[tid*5+3] = b3v; sh[tid*5+4] = b4v;
  if (tid == 0) *cnt = ch[0];                   // total active
  __syncthreads();
  // placement (order within bucket irrelevant; k_final recomputes exact rank)
  for (int j = tid; j < NB; j += 1024) {
    u32 bits = sbits[j];
    if (!bits) continue;
    int b = min((int)((bits >> SH) - BLO), NBUCK - 1);
    int pos = sh[b] + atomicAdd(&fl[b], 1);
    blist[pos] = ((u64)bits << 32) | (u64)(0xFFFFFFFFu - (u32)j);
  }
}

// ---------------- exact rank = base[b] + within-bucket greater-count; scatter ----------------
__global__ __launch_bounds__(256) void k_final(const u32* __restrict__ sbits,
    const int* __restrict__ base, const int* __restrict__ cnt,
    const u64* __restrict__ blist, const float* __restrict__ boxes,
    float* __restrict__ sboxes) {
  int i = blockIdx.x * 256 + threadIdx.x;
  if (i >= NB) return;
  u32 bits = sbits[i];
  if (!bits) return;
  int b = min((int)((bits >> SH) - BLO), NBUCK - 1);
  u64 key = ((u64)bits << 32) | (u64)(0xFFFFFFFFu - (u32)i);
  int s = base[b];
  int e = (b > 0) ? base[b-1] : *cnt;           // bucket size from adjacent suffix sums
  int r = s;
  for (int p = s; p < e; ++p) r += (blist[p] > key) ? 1 : 0;
  if (r < MAXC) ((float4*)sboxes)[r] = ((const float4*)boxes)[i];
}

// ------- pairwise IoU bitmask, upper-triangle blocks ONLY (lower-tri left unwritten) -------
__global__ __launch_bounds__(64) void k_iou(const float* __restrict__ sboxes,
    const int* __restrict__ cnt, u64* __restrict__ mask) {
#pragma clang fp contract(off)
  int N = min(*cnt, MAXC);
  int bi = blockIdx.x, bj = blockIdx.y;
  if (bj < bi) return;                // k_nms masks unwritten lower-tri words
  int t = threadIdx.x;
  int i = bi * 64 + t;
  if (bi * 64 >= N) return;
  __shared__ float4 jb[64];
  int j0 = bj * 64;
  if (j0 + t < N) jb[t] = ((const float4*)sboxes)[j0 + t];
  __syncthreads();
  if (i >= N) return;
  float4 a = ((const float4*)sboxes)[i];
  float areaA = (a.z - a.x + 1.0f) * (a.w - a.y + 1.0f);
  u64 word = 0;
  int jmax = min(64, N - j0);         // <=0 for pad word 79 -> writes 0
  for (int jj = 0; jj < jmax; ++jj) {
    int j = j0 + jj;
    if (j <= i) continue;
    float4 b = jb[jj];
    float iw = fminf(a.z, b.z) - fmaxf(a.x, b.x) + 1.0f;
    float ih = fminf(a.w, b.w) - fmaxf(a.y, b.y) + 1.0f;
    iw = fmaxf(iw, 0.0f);
    ih = fmaxf(ih, 0.0f);
    float inter = iw * ih;
    float areaB = (b.z - b.x + 1.0f) * (b.w - b.y + 1.0f);
    float iou = inter / (areaA + areaB - inter);
    if (iou > NMS_T) word |= (1ULL << jj);
  }
  mask[(size_t)i * NW + bj] = word;
}

// -------- serial greedy NMS: asm-forced 16-deep drain (all loads in flight, ONE vmcnt per trip) --------
__device__ __forceinline__ u64 rl64(u64 v, int l) {
  unsigned lo = __builtin_amdgcn_readlane((unsigned)(v & 0xffffffffULL), l);
  unsigned hi = __builtin_amdgcn_readlane((unsigned)(v >> 32), l);
  return ((u64)hi << 32) | (u64)lo;
}

__global__ __launch_bounds__(64, 1) void k_nms(const float* __restrict__ sboxes,
    const u64* __restrict__ mask, const int* __restrict__ cnt,
    float* __restrict__ out) {
  const int t = threadIdx.x;
  const int N = min(*cnt, MAXC);
  const int NBLK = (N + 63) >> 6;          // <= 79
  const int NSTEP = (NBLK + 3) >> 2;       // <= 20
  const int tt = (t < 40) ? t : 39;        // drain lane covers words 2tt, 2tt+1
  const bool lane_ok = (t < 40);
  const int w0i = 2 * tt, w1i = 2 * tt + 1;
  u64 rv0 = 0ULL, rv1 = 0ULL;              // remv: lane t owns words 2t, 2t+1 (t<40)
  __shared__ int klist[TOPN];
  int kept = 0;

  // diagonal 256x256 suppression block of current step: cc{g}{k} = word (wb+k) of row (sb+g*64+t)
  // only upper-tri words (k>=g) are written by k_iou
  u64 cc00=0,cc01=0,cc02=0,cc03=0, cc11=0,cc12=0,cc13=0, cc22=0,cc23=0, cc33=0;
#define CCL(g,k) { int rrow = sb + (g)*64 + t; rrow = (rrow < NRALLOC) ? rrow : 0; \
    cc##g##k = mask[(size_t)rrow * NW + (wb + (k))]; }
#define CC_ISSUE(S) { int sb = (S)*256, wb = (S)*4; \
    CCL(0,0) CCL(0,1) CCL(0,2) CCL(0,3) \
    CCL(1,1) CCL(1,2) CCL(1,3) \
    CCL(2,2) CCL(2,3) \
    CCL(3,3) }

  if (NSTEP > 0) CC_ISSUE(0);

  for (int s = 0; s < NSTEP; ++s) {
    const int cbase = s * 256;
    const int wb = s * 4;
    // carry-in from previously-kept rows + validity (word wi lives on lane wi>>1, slot wi&1)
    u64 av0, av1, av2, av3;
#define CARRY(K, dst) { int wi = wb + (K); \
      u64 w = rl64((wi & 1) ? rv1 : rv0, wi >> 1); \
      int rem = N - wi * 64; \
      u64 vm = (rem >= 64) ? ~0ULL : ((rem <= 0) ? 0ULL : ((1ULL << rem) - 1ULL)); \
      dst = ~w & vm; }
    CARRY(0, av0) CARRY(1, av1) CARRY(2, av2) CARRY(3, av3)
#undef CARRY
    int kept0 = kept;
    // scan: only alive candidates execute (all av values wave-uniform)
    for (;;) {
      int d;
      if (av0) d = (int)__builtin_ctzll(av0);
      else if (av1) d = 64 + (int)__builtin_ctzll(av1);
      else if (av2) d = 128 + (int)__builtin_ctzll(av2);
      else if (av3) d = 192 + (int)__builtin_ctzll(av3);
      else break;
      d = __builtin_amdgcn_readfirstlane(d);
      if (t == 0) klist[kept] = cbase + d;
      ++kept;
      if (kept >= TOPN) break;
      int l = d & 63;
      u64 s0 = 0, s1 = 0, s2 = 0, s3 = 0;
      switch (d >> 6) {
        case 0: s0 = rl64(cc00, l) | (1ULL << l); s1 = rl64(cc01, l); s2 = rl64(cc02, l); s3 = rl64(cc03, l); break;
        case 1: s1 = rl64(cc11, l) | (1ULL << l); s2 = rl64(cc12, l); s3 = rl64(cc13, l); break;
        case 2: s2 = rl64(cc22, l) | (1ULL << l); s3 = rl64(cc23, l); break;
        default: s3 = rl64(cc33, l) | (1ULL << l); break;
      }
      av0 &= ~s0; av1 &= ~s1; av2 &= ~s2; av3 &= ~s3;
    }
    if (kept >= TOPN) break;
    // prefetch next step's diagonal block — flies during the drain wait
    if (s + 1 < NSTEP) CC_ISSUE(s + 1);
    // drain kept rows: 16 asm loads issued back-to-back, ONE vmcnt(0) per trip
    int nk = kept - kept0;
    for (int c = 0; c < nk; c += 16) {
      int m = nk - c;
#define ROWK(K) int row##K = klist[(K < m) ? (kept0 + c + K) : 0];
      ROWK(0) ROWK(1) ROWK(2) ROWK(3) ROWK(4) ROWK(5) ROWK(6) ROWK(7)
      ROWK(8) ROWK(9) ROWK(10) ROWK(11) ROWK(12) ROWK(13) ROWK(14) ROWK(15)
#undef ROWK
#define LVK(K) u32x4 v##K; { const u64* ap##K = mask + (size_t)row##K * NW + 2 * (size_t)tt; \
      asm volatile("global_load_dwordx4 %0, %1, off" : "=v"(v##K) : "v"(ap##K)); }
      LVK(0) LVK(1) LVK(2) LVK(3) LVK(4) LVK(5) LVK(6) LVK(7)
      LVK(8) LVK(9) LVK(10) LVK(11) LVK(12) LVK(13) LVK(14) LVK(15)
#undef LVK
      asm volatile("s_waitcnt vmcnt(0)" ::: "memory");
      __builtin_amdgcn_sched_barrier(0);     // rule #18: keep consumers below the wait
      u64 o0 = 0, o1 = 0;
#define ACCK(K) { int bk = row##K >> 6; bool on = lane_ok && (K < m); \
      u64 lo = (((u64)(v##K).y) << 32) | (u64)(v##K).x; \
      u64 hi = (((u64)(v##K).w) << 32) | (u64)(v##K).z; \
      o0 |= (on && w0i >= bk) ? lo : 0ULL; \
      o1 |= (on && w1i >= bk) ? hi : 0ULL; }
      ACCK(0) ACCK(1) ACCK(2) ACCK(3) ACCK(4) ACCK(5) ACCK(6) ACCK(7)
      ACCK(8) ACCK(9) ACCK(10) ACCK(11) ACCK(12) ACCK(13) ACCK(14) ACCK(15)
#undef ACCK
      rv0 |= o0; rv1 |= o1;
    }
  }
  __syncthreads();
  // epilogue: write the FULL 300x5 output (zeros where unfilled)
  for (int e = t; e < TOPN * 5; e += 64) {
    int row = e / 5, col = e % 5;
    float v = 0.0f;
    if (col > 0 && row < kept) v = sboxes[klist[row] * 4 + (col - 1)];
    out[e] = v;
  }
}

extern "C" void kernel_launch(void* const* d_in, const int* in_sizes, int n_in,
                              void* d_out, int out_size, void* d_ws, size_t ws_size,
                              hipStream_t stream) {
  const float* cls  = (const float*)d_in[0];
  const float* pred = (const float*)d_in[1];
  const int*   imi  = (const int*)d_in[2];
  const float* mean = (const float*)d_in[3];
  const float* stdv = (const float*)d_in[4];
  float* out = (float*)d_out;

  char* ws = (char*)d_ws;
  float* boxes  = (float*)(ws);                        // NB*4 floats   = 277440 B
  u32*   sbits  = (u32*)(ws + 277440);                 // NB u32        = 69360 B
  float* sboxes = (float*)(ws + 346800);               // MAXC*4 floats = 80000 B
  int*   cnt    = (int*)(ws + 426800);                 // 16 B
  int*   base   = (int*)(ws + 426816);                 // NBUCK ints    = 20480 B
  u64*   mask   = (u64*)(ws + 447296);                 // NRALLOC*NW*8  = 3235840 B
  u64*   blist  = mask;   // alias: blist (<=138720 B) is dead before k_iou writes mask

  k_decode<<<(NB + 255) / 256, 256, 0, stream>>>(cls, pred, imi, mean, stdv, boxes, sbits);
  k_bucket<<<1, 1024, 0, stream>>>(sbits, base, cnt, blist);
  k_final<<<(NB + 255) / 256, 256, 0, stream>>>(sbits, base, cnt, blist, boxes, sboxes);
  dim3 giou((MAXC + 63) / 64, NW);
  k_iou<<<giou, 64, 0, stream>>>(sboxes, cnt, mask);
  k_nms<<<1, 64, 0, stream>>>(sboxes, mask, cnt, out);
}

// Round 10
// 101.473 us; speedup vs baseline: 1.3582x; 1.3582x over previous
//
#include <hip/hip_runtime.h>

#define NA 15
#define GH 34
#define GW 34
#define SP (GH*GW)          // 1156
#define NB (SP*NA)          // 17340
#define MAXC 5000
#define TOPN 300
#define NW 80               // padded words per mask row (79 used + 1 pad)
#define NRALLOC 5056        // mask rows allocated (79 blocks * 64)
#define THRESH_OBJ 0.2f
#define NMS_T 0.7f
// score-bucket constants: positive-float bits are order-preserving
#define SH 12
#define BLO 0x3E4CCu        // bits(0.2f) >> 12
#define NBUCK 5120          // covers bits(1.0)>>12 - BLO = 4916, 5 per scan-thread

typedef unsigned long long u64;
typedef unsigned int u32;
struct __align__(16) U2 { u64 x, y; };

__constant__ float c_aw[NA] = {45.3f,32.0f,22.6f,90.5f,64.0f,45.3f,181.0f,128.0f,90.5f,271.5f,192.0f,135.8f,362.0f,256.0f,181.0f};
__constant__ float c_ah[NA] = {22.6f,32.0f,45.3f,45.3f,64.0f,90.5f,90.5f,128.0f,181.0f,135.8f,192.0f,271.5f,181.0f,256.0f,362.0f};

// ---------------- decode: anchors + deltas -> clipped proposals + score bits ----------------
__global__ __launch_bounds__(256) void k_decode(
    const float* __restrict__ cls, const float* __restrict__ pred,
    const int* __restrict__ iminfo, const float* __restrict__ mean,
    const float* __restrict__ stdv, float* __restrict__ boxes,
    u32* __restrict__ sbits) {
#pragma clang fp contract(off)
  int r = blockIdx.x * 256 + threadIdx.x;
  if (r >= NB) return;
  int n = r % NA;
  int p = r / NA;       // p = h*GW + w
  int w = p % GW;
  int h = p / GW;

  float score = cls[(NA + n) * SP + p];             // channel NA+n, spatial p

  float d0 = pred[(n*4+0)*SP + p] * stdv[0] + mean[0];
  float d1 = pred[(n*4+1)*SP + p] * stdv[1] + mean[1];
  float d2 = pred[(n*4+2)*SP + p] * stdv[2] + mean[2];
  float d3 = pred[(n*4+3)*SP + p] * stdv[3] + mean[3];

  float aw = c_aw[n], ah = c_ah[n];
  float sx = (float)(w * 16);
  float sy = (float)(h * 16);
  float xmin = -0.5f * (aw - 1.0f) + sx;
  float ymin = -0.5f * (ah - 1.0f) + sy;
  float xmax =  0.5f * (aw - 1.0f) + sx;
  float ymax =  0.5f * (ah - 1.0f) + sy;

  float widths  = xmax - xmin + 1.0f;
  float heights = ymax - ymin + 1.0f;
  float ctrx = xmin + 0.5f * (widths - 1.0f);
  float ctry = ymin + 0.5f * (heights - 1.0f);

  float pcx = d0 * widths + ctrx;
  float pcy = d1 * heights + ctry;
  float pw = expf(d2) * widths;
  float ph = expf(d3) * heights;

  float x1 = pcx - 0.5f * (pw - 1.0f);
  float y1 = pcy - 0.5f * (ph - 1.0f);
  float x2 = pcx + 0.5f * (pw - 1.0f);
  float y2 = pcy + 0.5f * (ph - 1.0f);

  float ow = (float)iminfo[1] - 1.0f;
  float oh = (float)iminfo[0] - 1.0f;
  x1 = fminf(fmaxf(x1, 0.0f), ow);
  x2 = fminf(fmaxf(x2, 0.0f), ow);
  y1 = fminf(fmaxf(y1, 0.0f), oh);
  y2 = fminf(fmaxf(y2, 0.0f), oh);

  float ws = x2 - x1 + 1.0f;
  float hs = y2 - y1 + 1.0f;
  bool keep = (score > THRESH_OBJ) && (ws >= 6.0f) && (hs >= 6.0f);

  boxes[r*4+0] = x1;
  boxes[r*4+1] = y1;
  boxes[r*4+2] = x2;
  boxes[r*4+3] = y2;
  sbits[r] = keep ? __float_as_uint(score) : 0u;
}

// ------- fused: LDS histogram -> suffix scan -> base[], cnt -> bucket placement -------
__global__ __launch_bounds__(1024) void k_bucket(const u32* __restrict__ sbits,
    int* __restrict__ base, int* __restrict__ cnt, u64* __restrict__ blist) {
  __shared__ int sh[NBUCK];
  __shared__ int fl[NBUCK];
  __shared__ int ch[1024];
  int tid = threadIdx.x;
  for (int j = tid; j < NBUCK; j += 1024) { sh[j] = 0; fl[j] = 0; }
  __syncthreads();
  for (int j = tid; j < NB; j += 1024) {
    u32 bits = sbits[j];
    if (bits) { int b = min((int)((bits >> SH) - BLO), NBUCK - 1); atomicAdd(&sh[b], 1); }
  }
  __syncthreads();
  int c0 = sh[tid*5+0], c1 = sh[tid*5+1], c2 = sh[tid*5+2], c3 = sh[tid*5+3], c4 = sh[tid*5+4];
  ch[tid] = c0 + c1 + c2 + c3 + c4;
  __syncthreads();
  // Hillis-Steele inclusive suffix scan over chunk sums
  for (int off = 1; off < 1024; off <<= 1) {
    int v = ch[tid];
    int u = (tid + off < 1024) ? ch[tid + off] : 0;
    __syncthreads();
    ch[tid] = v + u;
    __syncthreads();
  }
  int S = (tid + 1 < 1024) ? ch[tid + 1] : 0;   // exclusive suffix of chunks after tid
  int b4v = S;
  int b3v = b4v + c4;
  int b2v = b3v + c3;
  int b1v = b2v + c2;
  int b0v = b1v + c1;
  base[tid*5+0] = b0v; base[tid*5+1] = b1v; base[tid*5+2] = b2v;
  base[tid*5+3] = b3v; base[tid*5+4] = b4v;
  sh[tid*5+0] = b0v; sh[tid*5+1] = b1v; sh[tid*5+2] = b2v;   // reuse sh as base
  sh[tid*5+3] = b3v; sh[tid*5+4] = b4v;
  if (tid == 0) *cnt = ch[0];                   // total active
  __syncthreads();
  // placement (order within bucket irrelevant; k_final recomputes exact rank)
  for (int j = tid; j < NB; j += 1024) {
    u32 bits = sbits[j];
    if (!bits) continue;
    int b = min((int)((bits >> SH) - BLO), NBUCK - 1);
    int pos = sh[b] + atomicAdd(&fl[b], 1);
    blist[pos] = ((u64)bits << 32) | (u64)(0xFFFFFFFFu - (u32)j);
  }
}

// ---------------- exact rank = base[b] + within-bucket greater-count; scatter ----------------
__global__ __launch_bounds__(256) void k_final(const u32* __restrict__ sbits,
    const int* __restrict__ base, const int* __restrict__ cnt,
    const u64* __restrict__ blist, const float* __restrict__ boxes,
    float* __restrict__ sboxes) {
  int i = blockIdx.x * 256 + threadIdx.x;
  if (i >= NB) return;
  u32 bits = sbits[i];
  if (!bits) return;
  int b = min((int)((bits >> SH) - BLO), NBUCK - 1);
  u64 key = ((u64)bits << 32) | (u64)(0xFFFFFFFFu - (u32)i);
  int s = base[b];
  int e = (b > 0) ? base[b-1] : *cnt;           // bucket size from adjacent suffix sums
  int r = s;
  for (int p = s; p < e; ++p) r += (blist[p] > key) ? 1 : 0;
  if (r < MAXC) ((float4*)sboxes)[r] = ((const float4*)boxes)[i];
}

// ------- pairwise IoU bitmask, upper-triangle blocks ONLY (lower-tri left unwritten) -------
__global__ __launch_bounds__(64) void k_iou(const float* __restrict__ sboxes,
    const int* __restrict__ cnt, u64* __restrict__ mask) {
#pragma clang fp contract(off)
  int N = min(*cnt, MAXC);
  int bi = blockIdx.x, bj = blockIdx.y;
  if (bj < bi) return;                // k_nms masks unwritten lower-tri words
  int t = threadIdx.x;
  int i = bi * 64 + t;
  if (bi * 64 >= N) return;
  __shared__ float4 jb[64];
  int j0 = bj * 64;
  if (j0 + t < N) jb[t] = ((const float4*)sboxes)[j0 + t];
  __syncthreads();
  if (i >= N) return;
  float4 a = ((const float4*)sboxes)[i];
  float areaA = (a.z - a.x + 1.0f) * (a.w - a.y + 1.0f);
  u64 word = 0;
  int jmax = min(64, N - j0);         // <=0 for pad word 79 -> writes 0
  for (int jj = 0; jj < jmax; ++jj) {
    int j = j0 + jj;
    if (j <= i) continue;
    float4 b = jb[jj];
    float iw = fminf(a.z, b.z) - fmaxf(a.x, b.x) + 1.0f;
    float ih = fminf(a.w, b.w) - fmaxf(a.y, b.y) + 1.0f;
    iw = fmaxf(iw, 0.0f);
    ih = fmaxf(ih, 0.0f);
    float inter = iw * ih;
    float areaB = (b.z - b.x + 1.0f) * (b.w - b.y + 1.0f);
    float iou = inter / (areaA + areaB - inter);
    if (iou > NMS_T) word |= (1ULL << jj);
  }
  mask[(size_t)i * NW + bj] = word;
}

// -------- serial greedy NMS: 64-blocks, branch-free 4x-unrolled scan, chunk-16 drain --------
__device__ __forceinline__ u64 rl64(u64 v, int l) {
  unsigned lo = __builtin_amdgcn_readlane((unsigned)(v & 0xffffffffULL), l);
  unsigned hi = __builtin_amdgcn_readlane((unsigned)(v >> 32), l);
  return ((u64)hi << 32) | (u64)lo;
}

__global__ __launch_bounds__(64, 1) void k_nms(const float* __restrict__ sboxes,
    const u64* __restrict__ mask, const int* __restrict__ cnt,
    float* __restrict__ out) {
  const int t = threadIdx.x;
  const int N = min(*cnt, MAXC);
  const int NBLK = (N + 63) >> 6;          // <= 79
  const int tt = (t < 40) ? t : 39;        // drain lane covers words 2tt, 2tt+1
  const bool lane_ok = (t < 40);
  const int w0i = 2 * tt, w1i = 2 * tt + 1;
  u64 rv0 = 0ULL, rv1 = 0ULL;              // remv: lane t owns words 2t, 2t+1 (t<40)
  __shared__ int klist[TOPN + 1];          // slot TOPN = dump for predicated-off stores
  int kept = 0;

  u64 colA = 0ULL, colB = 0ULL;            // ping-pong column gathers (lane d = row b*64+d, word b)
  if (NBLK > 0) colA = mask[(size_t)t * NW + 0];

  for (int b = 0; b < NBLK; ++b) {
    u64 cc = (b & 1) ? colB : colA;
    int base = b * 64;
    // carry-in from previously-kept rows + validity (word b lives on lane b>>1, slot b&1)
    u64 w = rl64((b & 1) ? rv1 : rv0, b >> 1);
    int nv = N - base; if (nv > 64) nv = 64;
    u64 valid = (nv >= 64) ? ~0ULL : ((1ULL << nv) - 1ULL);
    u64 avail = ~w & valid;
    int kept0 = kept;
    // branch-free 4x-unrolled scan: every sub-iteration is predicated scalar ALU
    while (avail && kept < TOPN) {
#pragma unroll
      for (int u = 0; u < 4; ++u) {
        bool on = (avail != 0ULL) && (kept < TOPN);
        int d = (int)__builtin_ctzll(avail | (1ULL << 63));  // ctz(0) guard; d in [0,63]
        klist[on ? kept : TOPN] = base + d;                  // all lanes, same addr+value
        u64 sup = rl64(cc, d);
        u64 clear = on ? (sup | (1ULL << d)) : 0ULL;
        avail &= ~clear;
        kept += on ? 1 : 0;
      }
    }
    if (kept >= TOPN) break;               // remaining drain is dead work
    // prefetch next block's column — latency hides under the drain wait
    if (b + 1 < NBLK) {
      u64 nx = mask[(size_t)((b + 1) * 64 + t) * NW + (b + 1)];
      if (b & 1) colA = nx; else colB = nx;
    }
    // drain kept rows: branch-free, one dwordx4 per row per lane, 16 rows per trip
    int nk = kept - kept0;
    for (int c = 0; c < nk; c += 16) {
      int m = nk - c;
#define ROWK(K) int row##K = klist[(K < m) ? (kept0 + c + K) : 0];
      ROWK(0) ROWK(1) ROWK(2) ROWK(3) ROWK(4) ROWK(5) ROWK(6) ROWK(7)
      ROWK(8) ROWK(9) ROWK(10) ROWK(11) ROWK(12) ROWK(13) ROWK(14) ROWK(15)
#undef ROWK
#define LVK(K) U2 v##K = ((const U2*)(mask + (size_t)row##K * NW))[tt];
      LVK(0) LVK(1) LVK(2) LVK(3) LVK(4) LVK(5) LVK(6) LVK(7)
      LVK(8) LVK(9) LVK(10) LVK(11) LVK(12) LVK(13) LVK(14) LVK(15)
#undef LVK
      u64 o0 = 0, o1 = 0;
#define ACCK(K) { int bk = row##K >> 6; bool on = lane_ok && (K < m); \
      o0 |= (on && w0i >= bk) ? v##K.x : 0ULL; \
      o1 |= (on && w1i >= bk) ? v##K.y : 0ULL; }
      ACCK(0) ACCK(1) ACCK(2) ACCK(3) ACCK(4) ACCK(5) ACCK(6) ACCK(7)
      ACCK(8) ACCK(9) ACCK(10) ACCK(11) ACCK(12) ACCK(13) ACCK(14) ACCK(15)
#undef ACCK
      rv0 |= o0; rv1 |= o1;
    }
  }
  __syncthreads();
  // epilogue: write the FULL 300x5 output (zeros where unfilled)
  for (int e = t; e < TOPN * 5; e += 64) {
    int row = e / 5, col = e % 5;
    float v = 0.0f;
    if (col > 0 && row < kept) v = sboxes[klist[row] * 4 + (col - 1)];
    out[e] = v;
  }
}

extern "C" void kernel_launch(void* const* d_in, const int* in_sizes, int n_in,
                              void* d_out, int out_size, void* d_ws, size_t ws_size,
                              hipStream_t stream) {
  const float* cls  = (const float*)d_in[0];
  const float* pred = (const float*)d_in[1];
  const int*   imi  = (const int*)d_in[2];
  const float* mean = (const float*)d_in[3];
  const float* stdv = (const float*)d_in[4];
  float* out = (float*)d_out;

  char* ws = (char*)d_ws;
  float* boxes  = (float*)(ws);                        // NB*4 floats   = 277440 B
  u32*   sbits  = (u32*)(ws + 277440);                 // NB u32        = 69360 B
  float* sboxes = (float*)(ws + 346800);               // MAXC*4 floats = 80000 B
  int*   cnt    = (int*)(ws + 426800);                 // 16 B
  int*   base   = (int*)(ws + 426816);                 // NBUCK ints    = 20480 B
  u64*   mask   = (u64*)(ws + 447296);                 // NRALLOC*NW*8  = 3235840 B
  u64*   blist  = mask;   // alias: blist (<=138720 B) is dead before k_iou writes mask

  k_decode<<<(NB + 255) / 256, 256, 0, stream>>>(cls, pred, imi, mean, stdv, boxes, sbits);
  k_bucket<<<1, 1024, 0, stream>>>(sbits, base, cnt, blist);
  k_final<<<(NB + 255) / 256, 256, 0, stream>>>(sbits, base, cnt, blist, boxes, sboxes);
  dim3 giou((MAXC + 63) / 64, NW);
  k_iou<<<giou, 64, 0, stream>>>(sboxes, cnt, mask);
  k_nms<<<1, 64, 0, stream>>>(sboxes, mask, cnt, out);
}